// Round 17
// baseline (189.789 us; speedup 1.0000x reference)
//
#include <hip/hip_runtime.h>
#include <hip/hip_bf16.h>

#define NN 100000
#define MM 20000
#define EE 1000000
#define FF 128

// binned CSR build parameters
#define EBK 157    // ceil(MM/128) edge buckets
#define NBK 782    // ceil(NN/128) node buckets
#define ECAP 7168  // per-edge-bucket capacity (mean 6400, sigma ~80)
#define NCAP 1664  // per-node-bucket capacity (mean 1280, sigma ~36)
#define CHUNK 2048 // 489 combined binA blocks
#define NREP 64    // bn_partial replication factor
#define BM 32      // gemm row-tile (32*3125 == NN exactly)
#define GEMM_BLOCKS (NN / BM)               // 3125
#define AEDGE_BLOCKS (MM / 4)               // 5000 (4 edges/block exactly)
#define BINA_BLOCKS ((EE + CHUNK - 1) / CHUNK) // 489
#define SMEM_BYTES 8448                     // max(gemm 8320, binA 7512)

typedef unsigned short u16;
typedef unsigned int u32;
typedef __attribute__((ext_vector_type(8))) short short8v;
typedef __attribute__((ext_vector_type(4))) float f32x4;

__device__ __forceinline__ u16 f2bf(float f) {
  u32 x = __float_as_uint(f);
  return (u16)((x + 0x7FFFu + ((x >> 16) & 1u)) >> 16);
}
__device__ __forceinline__ float bf2f(u16 u) { return __uint_as_float(((u32)u) << 16); }
__device__ __forceinline__ float leaky(float v) { return v > 0.f ? v : 0.2f * v; }
__device__ __forceinline__ float readlane_f(float v, int l) {
  return __uint_as_float((u32)__builtin_amdgcn_readlane((int)__float_as_uint(v), l));
}

// ---------------------------------------------------------------------------
// k_prep: zero ecur/ncur/bn_partial; block 0 computes watt2 and WtSwz. grid 64.
// ---------------------------------------------------------------------------
__global__ __launch_bounds__(256) void k_prep(const float* __restrict__ W,
                                              const float* __restrict__ att,
                                              float* __restrict__ watt2, u16* __restrict__ WtSwz,
                                              int* __restrict__ ecur, int* __restrict__ ncur,
                                              float* __restrict__ bn_partial) {
  int gid = blockIdx.x * 256 + threadIdx.x;
  if (gid < EBK) ecur[gid] = 0;
  if (gid < NBK) ncur[gid] = 0;
  if (gid < NREP * 256) bn_partial[gid] = 0.f;
  if (blockIdx.x == 0 && threadIdx.x < 128) {
    int t = threadIdx.x;
    float s2 = 0.f;
    for (int c = 0; c < FF; c += 4) {
      float4 wv = *(const float4*)(W + t * FF + c);
      s2 += wv.x * att[FF + c] + wv.y * att[FF + c + 1] + wv.z * att[FF + c + 2] + wv.w * att[FF + c + 3];
    }
    watt2[t] = s2;
    int c = t;
    for (int k = 0; k < FF; k += 2) {
      u32 p = (u32)f2bf(W[k * FF + c]) | ((u32)f2bf(W[(k + 1) * FF + c]) << 16);
      int byte = c * 256 + ((k * 2) ^ ((c & 7) << 4));
      *(u32*)((char*)WtSwz + byte) = p;
    }
  }
}

// ---------------------------------------------------------------------------
// k_mega: three independent jobs in one launch. Latency-bound binning FIRST so
// it overlaps the BW-bound gemm/aedge stream:
//   blocks [0, BINA):          combined two-sided binned scatter (LDS hist ->
//                              one reserve atomic per (block,bucket) -> scatter)
//   blocks [+, GEMM_BLOCKS):   xw = bf16(x@W) + fused a_node (MFMA, BM=32),
//                              B-fragments direct from L2-resident WtSwz
//   blocks [+, AEDGE_BLOCKS):  a_edge = he . watt2 (wave per row)
// History: binning LAST = serial sum (R14, 73us). CHUNK 4096 combined-first =
// 245 blocks, 60us span = critical path (R15). Side-split 2048-first doubled
// pass-2 index traffic + 978 low-ILP blocks stole gemm issue slots (R16, 69us).
// This: combined, first, 489 blocks.
// ---------------------------------------------------------------------------
__global__ __launch_bounds__(256) void k_mega(const float* __restrict__ x,
                                              const u16* __restrict__ WtSwz,
                                              const float* __restrict__ att,
                                              u16* __restrict__ xw,
                                              float* __restrict__ a_node,
                                              const float* __restrict__ he,
                                              const float* __restrict__ watt2,
                                              float* __restrict__ a_edge,
                                              const int* __restrict__ node_idx,
                                              const int* __restrict__ edge_idx,
                                              int* __restrict__ ecur, int* __restrict__ ncur,
                                              u32* __restrict__ ebins, u32* __restrict__ nbins) {
  __shared__ char smem[SMEM_BYTES];
  int t = threadIdx.x;
  int bid = blockIdx.x;

  if (bid < BINA_BLOCKS) {
    // ---- combined binA branch (two-pass LDS histogram; per-lane global
    //      atomics serialize 64-deep at L2: 674us — don't) ----
    int* ecnt = (int*)smem;
    int* ncnt = ecnt + EBK;
    int* ebase = ncnt + NBK;
    int* nbase = ebase + EBK;
    for (int i = t; i < EBK; i += 256) ecnt[i] = 0;
    for (int i = t; i < NBK; i += 256) ncnt[i] = 0;
    __syncthreads();
    int start = bid * CHUNK;
    int end = min(start + CHUNK, EE);
    for (int e = start + t; e < end; e += 256) {
      int m = edge_idx[e], n = node_idx[e];
      atomicAdd(&ecnt[m >> 7], 1);
      atomicAdd(&ncnt[n >> 7], 1);
    }
    __syncthreads();
    for (int i = t; i < EBK; i += 256) {
      int c = ecnt[i];
      ebase[i] = c ? atomicAdd(&ecur[i], c) : 0;
      ecnt[i] = 0;
    }
    for (int i = t; i < NBK; i += 256) {
      int c = ncnt[i];
      nbase[i] = c ? atomicAdd(&ncur[i], c) : 0;
      ncnt[i] = 0;
    }
    __syncthreads();
    for (int e = start + t; e < end; e += 256) {
      int m = edge_idx[e], n = node_idx[e];
      int eb = m >> 7, nb = n >> 7;
      int p = ebase[eb] + atomicAdd(&ecnt[eb], 1);
      if (p < ECAP) ebins[(size_t)eb * ECAP + p] = ((u32)n << 7) | (u32)(m & 127);
      int q = nbase[nb] + atomicAdd(&ncnt[nb], 1);
      if (q < NCAP) nbins[(size_t)nb * NCAP + q] = ((u32)m << 7) | (u32)(n & 127);
    }
    return;
  }

  if (bid >= BINA_BLOCKS + GEMM_BLOCKS) {
    // ---- a_edge branch: wave per hyperedge row (4*AEDGE_BLOCKS == MM) ----
    int m = ((bid - BINA_BLOCKS - GEMM_BLOCKS) * 256 + t) >> 6;
    int lane = t & 63;
    float2 wv = ((const float2*)watt2)[lane];
    float2 v = ((const float2*)(he + (size_t)m * FF))[lane];
    float p = v.x * wv.x + v.y * wv.y;
#pragma unroll
    for (int off = 32; off; off >>= 1) p += __shfl_xor(p, off, 64);
    if (lane == 0) a_edge[m] = p;
    return;
  }

  // ---- gemm branch ----
  u16* xl = (u16*)smem;                  // 8 KB swizzled [r][k]
  float* pn = (float*)(smem + 8192);     // 128 B
  if (t < BM) pn[t] = 0.f;
  int row0 = (bid - BINA_BLOCKS) * BM;   // 32*3125 == NN: no bounds checks
  for (int chunk = t; chunk < BM * 32; chunk += 256) {
    int r = chunk >> 5;
    int j = chunk & 31;
    float4 v = ((const float4*)(x + (size_t)(row0 + r) * FF))[j];
    uint2 p;
    p.x = (u32)f2bf(v.x) | ((u32)f2bf(v.y) << 16);
    p.y = (u32)f2bf(v.z) | ((u32)f2bf(v.w) << 16);
    int byte = r * 256 + ((j * 8) ^ ((r & 7) << 4));
    *(uint2*)((char*)xl + byte) = p;
  }
  __syncthreads();

  int wid = t >> 6, lane = t & 63;
  int rt = wid & 1, ch = wid >> 1;
  int r_lo = lane & 15, khalf = lane >> 4;
  f32x4 acc[4];
#pragma unroll
  for (int ct = 0; ct < 4; ++ct) acc[ct] = (f32x4){0.f, 0.f, 0.f, 0.f};

#pragma unroll
  for (int kc = 0; kc < 4; ++kc) {
    int kbyte = kc * 64 + khalf * 16;
    int arow = rt * 16 + r_lo;
    short8v a = *(const short8v*)((const char*)xl + arow * 256 + (kbyte ^ ((arow & 7) << 4)));
#pragma unroll
    for (int ct = 0; ct < 4; ++ct) {
      int brow = ch * 64 + ct * 16 + r_lo;
      short8v b = *(const short8v*)((const char*)WtSwz + brow * 256 + (kbyte ^ ((brow & 7) << 4)));
      acc[ct] = __builtin_amdgcn_mfma_f32_16x16x32_bf16(a, b, acc[ct], 0, 0, 0);
    }
  }

  float att_c[4];
#pragma unroll
  for (int ct = 0; ct < 4; ++ct) att_c[ct] = att[ch * 64 + ct * 16 + r_lo];
  float p[4] = {0.f, 0.f, 0.f, 0.f};
#pragma unroll
  for (int ct = 0; ct < 4; ++ct) {
#pragma unroll
    for (int reg = 0; reg < 4; ++reg) {
      int lrow = rt * 16 + khalf * 4 + reg;
      xw[(size_t)(row0 + lrow) * FF + ch * 64 + ct * 16 + r_lo] = f2bf(acc[ct][reg]);
      p[reg] += acc[ct][reg] * att_c[ct];
    }
  }
#pragma unroll
  for (int off = 1; off <= 8; off <<= 1) {
#pragma unroll
    for (int reg = 0; reg < 4; ++reg) p[reg] += __shfl_xor(p[reg], off, 64);
  }
  if (r_lo == 0) {
#pragma unroll
    for (int reg = 0; reg < 4; ++reg)
      atomicAdd(&pn[rt * 16 + khalf * 4 + reg], p[reg]);
  }
  __syncthreads();
  if (t < BM) a_node[row0 + t] = pn[t];
}

// ---------------------------------------------------------------------------
// k_binB: one block per bucket (edge then node). Inline prefix for the base,
// counting-sort into CSR. Emits packed (other_idx, uw) uint2 pairs where
// uw = exp(leaky(a_node[n] + a_edge[m])) (one operand LDS-local per side).
// ---------------------------------------------------------------------------
__global__ __launch_bounds__(256) void k_binB(const u32* __restrict__ ebins,
                                              const int* __restrict__ ecur,
                                              int* __restrict__ edge_ptr,
                                              uint2* __restrict__ pairE,
                                              const u32* __restrict__ nbins,
                                              const int* __restrict__ ncur,
                                              int* __restrict__ node_ptr,
                                              uint2* __restrict__ pairN,
                                              const float* __restrict__ a_node,
                                              const float* __restrict__ a_edge) {
  __shared__ int cnt[128], cur[128], sc[128];
  __shared__ int ps[256];
  __shared__ float loc[128];
  int t = threadIdx.x;
  bool is_edge = blockIdx.x < EBK;
  int b = is_edge ? blockIdx.x : blockIdx.x - EBK;
  const int* curArr = is_edge ? ecur : ncur;
  const u32* src = is_edge ? (ebins + (size_t)b * ECAP) : (nbins + (size_t)b * NCAP);
  int count = is_edge ? min(ecur[b], ECAP) : min(ncur[b], NCAP);
  int* ptr = is_edge ? edge_ptr : node_ptr;
  uint2* pairArr = is_edge ? pairE : pairN;
  const float* gatherA = is_edge ? a_node : a_edge;  // indexed by 'other'
  int glen = is_edge ? MM : NN;
  int nbk = is_edge ? EBK : NBK;

  if (t < 128) {
    int g = b * 128 + t;
    loc[t] = (g < glen) ? (is_edge ? a_edge[g] : a_node[g]) : 0.f;
  }

  // inline exclusive prefix: gbase = sum(curArr[0..b))
  int acc = 0;
  for (int i = t; i < b; i += 256) acc += curArr[i];
  ps[t] = acc;
  __syncthreads();
  for (int off = 128; off; off >>= 1) {
    if (t < off) ps[t] += ps[t + off];
    __syncthreads();
  }
  int gbase = ps[0];

  if (t < 128) cnt[t] = 0;
  __syncthreads();
  for (int i = t; i < count; i += 256) atomicAdd(&cnt[src[i] & 127], 1);
  __syncthreads();
  if (t < 128) sc[t] = cnt[t];
  __syncthreads();
  for (int off = 1; off < 128; off <<= 1) {
    int u = (t >= off && t < 128) ? sc[t - off] : 0;
    __syncthreads();
    if (t < 128) sc[t] += u;
    __syncthreads();
  }
  if (t < 128) {
    int excl = sc[t] - cnt[t];
    cur[t] = excl;
    int g = b * 128 + t;
    if (g < glen) ptr[g] = gbase + excl;
  }
  if (b == nbk - 1 && t == 0) ptr[glen] = gbase + count;
  __syncthreads();
  for (int i = t; i < count; i += 256) {
    u32 v = src[i];
    int lo = v & 127;
    int other = (int)(v >> 7);
    int pos = atomicAdd(&cur[lo], 1);
    float uw = __expf(leaky(gatherA[other] + loc[lo]));
    pairArr[gbase + pos] = make_uint2((u32)other, __float_as_uint(uw));
  }
}

// ---------------------------------------------------------------------------
// k_edge_agg: per-edge normalization + node->edge aggregation (wave per edge,
// 4 edges/block exactly). Coalesced ptr prefetch via lane<5 + readlane.
// Writes ef'[m] = ef[m]*invs so node_agg needs no invsE. No max-subtraction.
// ---------------------------------------------------------------------------
__global__ __launch_bounds__(256) void k_edge_agg(const int* __restrict__ edge_ptr,
                                                  const uint2* __restrict__ pairE,
                                                  const u16* __restrict__ xw,
                                                  u16* __restrict__ edge_feat) {
  int wid = threadIdx.x >> 6, lane = threadIdx.x & 63;
  int m = blockIdx.x * 4 + wid;   // 4*gridDim == MM exactly
  int pv_l = (lane < 5) ? edge_ptr[blockIdx.x * 4 + lane] : 0;
  int s0 = __builtin_amdgcn_readlane(pv_l, wid);
  int s1 = __builtin_amdgcn_readlane(pv_l, wid + 1);
  int len = s1 - s0;
  if (len == 0) return;

  float ssum_l = 0.f;
  float accx = 0.f, accy = 0.f;
  for (int base = s0; base < s1; base += 64) {
    int i = base + lane;
    bool valid = i < s1;
    uint2 pv = valid ? pairE[i] : make_uint2(0u, 0u);
    int n_l = (int)pv.x;
    float w_l = __uint_as_float(pv.y);   // 0.0f for invalid lanes
    ssum_l += w_l;
    int cnt = min(64, s1 - base);
    for (int b = 0; b < cnt; b += 16) {
      u32 u[16];
      float wv[16];
#pragma unroll
      for (int j = 0; j < 16; ++j) {
        int n = __builtin_amdgcn_readlane(n_l, b + j);
        wv[j] = readlane_f(w_l, b + j);
        u[j] = *(const u32*)(xw + (size_t)n * FF + 2 * lane);
      }
#pragma unroll
      for (int j = 0; j < 16; ++j) {
        accx += wv[j] * bf2f((u16)u[j]);
        accy += wv[j] * bf2f((u16)(u[j] >> 16));
      }
    }
  }
#pragma unroll
  for (int off = 1; off < 64; off <<= 1) ssum_l += __shfl_xor(ssum_l, off, 64);
  float invs = 1.0f / (ssum_l + 1e-16f);
  float r = invs * invs / (float)len;   // ef' = ef * invs
  u32 packed = (u32)f2bf(accx * r) | ((u32)f2bf(accy * r) << 16);
  *(u32*)(edge_feat + (size_t)m * FF + 2 * lane) = packed;
}

// ---------------------------------------------------------------------------
// k_node_agg: edge->node aggregation, 4 nodes per wave (grid*16 == NN exactly),
// coalesced ptr prefetch, fused BN partial stats. w = uw (ef pre-divided by S).
// ---------------------------------------------------------------------------
__global__ __launch_bounds__(256) void k_node_agg(const int* __restrict__ node_ptr,
                                                  const uint2* __restrict__ pairN,
                                                  const u16* __restrict__ edge_feat,
                                                  const float* __restrict__ bias,
                                                  float* __restrict__ out_f32,
                                                  u16* __restrict__ raw_bf,
                                                  float* __restrict__ bn_partial) {
  __shared__ float4 sd[4][64];
  int wid = threadIdx.x >> 6, lane = threadIdx.x & 63;
  float2 bv = ((const float2*)bias)[lane];
  int n0 = blockIdx.x * 16 + wid * 4;
  int pv_l = (lane < 5) ? node_ptr[n0 + lane] : 0;   // ptr[n0..n0+4]
  float s1x = 0.f, s1y = 0.f, s2x = 0.f, s2y = 0.f;
#pragma unroll
  for (int k = 0; k < 4; ++k) {
    int n = n0 + k;   // grid sized so n < NN always
    int s0 = __builtin_amdgcn_readlane(pv_l, k);
    int s1 = __builtin_amdgcn_readlane(pv_l, k + 1);
    float accx = 0.f, accy = 0.f;
    for (int base = s0; base < s1; base += 64) {
      int i = base + lane;
      bool valid = i < s1;
      uint2 pv = valid ? pairN[i] : make_uint2(0u, 0u);
      int m_l = (int)pv.x;
      float w_l = __uint_as_float(pv.y);   // 0.0f for invalid lanes
      int cnt = min(64, s1 - base);
      for (int b = 0; b < cnt; b += 16) {
        u32 u[16];
        float wv[16];
#pragma unroll
        for (int j = 0; j < 16; ++j) {
          int mm = __builtin_amdgcn_readlane(m_l, b + j);
          wv[j] = readlane_f(w_l, b + j);
          u[j] = *(const u32*)(edge_feat + (size_t)mm * FF + 2 * lane);
        }
#pragma unroll
        for (int j = 0; j < 16; ++j) {
          accx += wv[j] * bf2f((u16)u[j]);
          accy += wv[j] * bf2f((u16)(u[j] >> 16));
        }
      }
    }
    int deg = s1 - s0;
    float dinv = deg > 0 ? 1.0f / (float)deg : 0.f;
    float ox = accx * dinv + bv.x;
    float oy = accy * dinv + bv.y;
    if (raw_bf) {
      *(u32*)(raw_bf + (size_t)n * FF + 2 * lane) = (u32)f2bf(ox) | ((u32)f2bf(oy) << 16);
    } else {
      ((float2*)(out_f32 + (size_t)n * FF))[lane] = make_float2(ox, oy);
    }
    s1x += ox; s1y += oy;
    s2x += ox * ox; s2y += oy * oy;
  }
  sd[wid][lane] = make_float4(s1x, s1y, s2x, s2y);
  __syncthreads();
  if (wid == 0) {
    float4 a0 = sd[0][lane], a1 = sd[1][lane], a2 = sd[2][lane], a3 = sd[3][lane];
    float4 s;
    s.x = a0.x + a1.x + a2.x + a3.x;
    s.y = a0.y + a1.y + a2.y + a3.y;
    s.z = a0.z + a1.z + a2.z + a3.z;
    s.w = a0.w + a1.w + a2.w + a3.w;
    float* bp = bn_partial + (blockIdx.x & (NREP - 1)) * 256;
    atomicAdd(bp + 2 * lane, s.x);
    atomicAdd(bp + 2 * lane + 1, s.y);
    atomicAdd(bp + 128 + 2 * lane, s.z);
    atomicAdd(bp + 128 + 2 * lane + 1, s.w);
  }
}

// ---------------------------------------------------------------------------
// k_bn_final: reduce bn_partial replicas -> BN scale/shift
// ---------------------------------------------------------------------------
__global__ void k_bn_final(const float* __restrict__ bn_partial, const float* __restrict__ gamma,
                           const float* __restrict__ beta, float* __restrict__ ss) {
  int c = threadIdx.x; // 128
  float s1 = 0.f, s2 = 0.f;
  for (int r = 0; r < NREP; ++r) {
    s1 += bn_partial[r * 256 + c];
    s2 += bn_partial[r * 256 + 128 + c];
  }
  float mu = s1 * (1.0f / NN);
  float var = s2 * (1.0f / NN) - mu * mu;
  var = fmaxf(var, 0.f);
  float sc = gamma[c] * rsqrtf(var + 1e-5f);
  ss[c] = sc;
  ss[FF + c] = beta[c] - mu * sc;
}

// ---------------------------------------------------------------------------
// k_finalize: BN + ELU + residual. Reads raw (bf16 if raw_bf, else out in place).
// ---------------------------------------------------------------------------
__global__ __launch_bounds__(256) void k_finalize(float* __restrict__ out,
                                                  const u16* __restrict__ raw_bf,
                                                  const float* __restrict__ x,
                                                  const float* __restrict__ ss) {
  int idx = blockIdx.x * 256 + threadIdx.x;  // float4 index
  float4 v;
  if (raw_bf) {
    ushort4 rv = *(const ushort4*)(raw_bf + (size_t)idx * 4);
    v = make_float4(bf2f(rv.x), bf2f(rv.y), bf2f(rv.z), bf2f(rv.w));
  } else {
    v = ((const float4*)out)[idx];
  }
  float4 xr = ((const float4*)x)[idx];
  int cb = (idx * 4) & 127;
  float4 sc = *(const float4*)(ss + cb);
  float4 sh = *(const float4*)(ss + FF + cb);
  v.x = fmaf(v.x, sc.x, sh.x);
  v.y = fmaf(v.y, sc.y, sh.y);
  v.z = fmaf(v.z, sc.z, sh.z);
  v.w = fmaf(v.w, sc.w, sh.w);
  v.x = v.x > 0.f ? v.x : expm1f(v.x);
  v.y = v.y > 0.f ? v.y : expm1f(v.y);
  v.z = v.z > 0.f ? v.z : expm1f(v.z);
  v.w = v.w > 0.f ? v.w : expm1f(v.w);
  v.x += xr.x; v.y += xr.y; v.z += xr.z; v.w += xr.w;
  ((float4*)out)[idx] = v;
}

// ---------------------------------------------------------------------------
extern "C" void kernel_launch(void* const* d_in, const int* in_sizes, int n_in,
                              void* d_out, int out_size, void* d_ws, size_t ws_size,
                              hipStream_t stream) {
  const float* x     = (const float*)d_in[0];
  const float* he    = (const float*)d_in[1];
  const float* W     = (const float*)d_in[2];
  const float* att   = (const float*)d_in[3];
  const float* bias  = (const float*)d_in[4];
  const float* gamma = (const float*)d_in[5];
  const float* beta  = (const float*)d_in[6];
  const int* node_idx = (const int*)d_in[7];
  const int* edge_idx = (const int*)d_in[8];
  float* out = (float*)d_out;

  char* w = (char*)d_ws;
  auto alloc = [&](size_t bytes) -> char* {
    char* p = w;
    w += (bytes + 255) & ~(size_t)255;
    return p;
  };
  u16*   xw        = (u16*)  alloc((size_t)NN * FF * 2);
  float* a_node    = (float*)alloc((size_t)NN * 4);
  float* a_edge    = (float*)alloc((size_t)MM * 4);
  u16*   WtSwz     = (u16*)  alloc((size_t)FF * FF * 2);
  float* watt2     = (float*)alloc(FF * 4);
  u16*   edge_feat = (u16*)  alloc((size_t)MM * FF * 2);
  int* edge_ptr    = (int*)  alloc((size_t)(MM + 1) * 4);
  int* node_ptr    = (int*)  alloc((size_t)(NN + 1) * 4);
  uint2* pairE     = (uint2*)alloc((size_t)EE * 8);
  uint2* pairN     = (uint2*)alloc((size_t)EE * 8);
  int* ecur        = (int*)  alloc((size_t)EBK * 4);
  int* ncur        = (int*)  alloc((size_t)NBK * 4);
  u32* ebins       = (u32*)  alloc((size_t)EBK * ECAP * 4);
  u32* nbins       = (u32*)  alloc((size_t)NBK * NCAP * 4);
  float* bn_partial= (float*)alloc((size_t)NREP * 256 * 4);
  float* ss        = (float*)alloc(2 * FF * 4);
  u16*   raw_cand  = (u16*)  alloc((size_t)NN * FF * 2);  // bf16 raw staging (optional)
  size_t need = (size_t)(w - (char*)d_ws);
  u16* raw_bf = (need <= ws_size) ? raw_cand : (u16*)nullptr;

  k_prep<<<64, 256, 0, stream>>>(W, att, watt2, WtSwz, ecur, ncur, bn_partial);
  k_mega<<<BINA_BLOCKS + GEMM_BLOCKS + AEDGE_BLOCKS, 256, 0, stream>>>(
      x, WtSwz, att, xw, a_node, he, watt2, a_edge,
      node_idx, edge_idx, ecur, ncur, ebins, nbins);

  k_binB<<<EBK + NBK, 256, 0, stream>>>(ebins, ecur, edge_ptr, pairE,
                                        nbins, ncur, node_ptr, pairN,
                                        a_node, a_edge);

  k_edge_agg<<<MM / 4, 256, 0, stream>>>(edge_ptr, pairE, xw, edge_feat);
  k_node_agg<<<NN / 16, 256, 0, stream>>>(node_ptr, pairN, edge_feat, bias, out, raw_bf, bn_partial);
  k_bn_final<<<1, 128, 0, stream>>>(bn_partial, gamma, beta, ss);
  k_finalize<<<(NN * FF / 4 + 255) / 256, 256, 0, stream>>>(out, raw_bf, x, ss);
}

// Round 18
// 172.233 us; speedup vs baseline: 1.1019x; 1.1019x over previous
//
#include <hip/hip_runtime.h>
#include <hip/hip_bf16.h>

#define NN 100000
#define MM 20000
#define EE 1000000
#define FF 128

// binned CSR build parameters
#define EBK 157     // ceil(MM/128) edge buckets
#define NBK 782     // ceil(NN/128) node buckets
#define NREPL 8     // reserve-counter replication (cuts atomic chains 256->32)
#define ECAPR 1024  // per-(edge bucket, replica) capacity (mean 800, +7.9 sigma)
#define NCAPR 256   // per-(node bucket, replica) capacity (mean 160, +7.6 sigma)
#define CHUNK 3907  // ceil(EE/256) -> exactly 256 binA blocks (~1/CU)
#define NREP 64     // bn_partial replication factor
#define BM 32       // gemm row-tile (32*3125 == NN exactly)
#define GEMM_BLOCKS (NN / BM)               // 3125
#define AEDGE_BLOCKS (MM / 4)               // 5000 (4 edges/block exactly)
#define BINA_BLOCKS 256
#define SMEM_BYTES 8448                     // max(gemm 8320, binA 7512)

typedef unsigned short u16;
typedef unsigned int u32;
typedef __attribute__((ext_vector_type(8))) short short8v;
typedef __attribute__((ext_vector_type(4))) float f32x4;

__device__ __forceinline__ u16 f2bf(float f) {
  u32 x = __float_as_uint(f);
  return (u16)((x + 0x7FFFu + ((x >> 16) & 1u)) >> 16);
}
__device__ __forceinline__ float bf2f(u16 u) { return __uint_as_float(((u32)u) << 16); }
__device__ __forceinline__ float leaky(float v) { return v > 0.f ? v : 0.2f * v; }
__device__ __forceinline__ float readlane_f(float v, int l) {
  return __uint_as_float((u32)__builtin_amdgcn_readlane((int)__float_as_uint(v), l));
}

// ---------------------------------------------------------------------------
// k_prep: zero ecur/ncur/bn_partial; block 0 computes watt2 and WtSwz. grid 64.
// ---------------------------------------------------------------------------
__global__ __launch_bounds__(256) void k_prep(const float* __restrict__ W,
                                              const float* __restrict__ att,
                                              float* __restrict__ watt2, u16* __restrict__ WtSwz,
                                              int* __restrict__ ecur, int* __restrict__ ncur,
                                              float* __restrict__ bn_partial) {
  int gid = blockIdx.x * 256 + threadIdx.x;
  if (gid < NREPL * EBK) ecur[gid] = 0;
  if (gid < NREPL * NBK) ncur[gid] = 0;
  if (gid < NREP * 256) bn_partial[gid] = 0.f;
  if (blockIdx.x == 0 && threadIdx.x < 128) {
    int t = threadIdx.x;
    float s2 = 0.f;
    for (int c = 0; c < FF; c += 4) {
      float4 wv = *(const float4*)(W + t * FF + c);
      s2 += wv.x * att[FF + c] + wv.y * att[FF + c + 1] + wv.z * att[FF + c + 2] + wv.w * att[FF + c + 3];
    }
    watt2[t] = s2;
    int c = t;
    for (int k = 0; k < FF; k += 2) {
      u32 p = (u32)f2bf(W[k * FF + c]) | ((u32)f2bf(W[(k + 1) * FF + c]) << 16);
      int byte = c * 256 + ((k * 2) ^ ((c & 7) << 4));
      *(u32*)((char*)WtSwz + byte) = p;
    }
  }
}

// ---------------------------------------------------------------------------
// k_mega: three independent jobs in one launch. Latency-bound binning FIRST so
// it overlaps the BW-bound gemm/aedge stream (R14: binning last = serial sum).
//   blocks [0, 256):           combined two-sided binned scatter. Reserve
//     counters are 8-way REPLICATED (replica = bid&7): R15-R17 showed ~10us of
//     per-block fixed cost was 939 reserve atomics x 256-deep L2 chains.
//   blocks [+, GEMM_BLOCKS):   xw = bf16(x@W) + fused a_node (MFMA, BM=32),
//                              B-fragments direct from L2-resident WtSwz
//   blocks [+, AEDGE_BLOCKS):  a_edge = he . watt2 (wave per row)
// ---------------------------------------------------------------------------
__global__ __launch_bounds__(256) void k_mega(const float* __restrict__ x,
                                              const u16* __restrict__ WtSwz,
                                              const float* __restrict__ att,
                                              u16* __restrict__ xw,
                                              float* __restrict__ a_node,
                                              const float* __restrict__ he,
                                              const float* __restrict__ watt2,
                                              float* __restrict__ a_edge,
                                              const int* __restrict__ node_idx,
                                              const int* __restrict__ edge_idx,
                                              int* __restrict__ ecur, int* __restrict__ ncur,
                                              u32* __restrict__ ebins, u32* __restrict__ nbins) {
  __shared__ char smem[SMEM_BYTES];
  int t = threadIdx.x;
  int bid = blockIdx.x;

  if (bid < BINA_BLOCKS) {
    // ---- combined binA branch (two-pass LDS histogram; per-lane global
    //      atomics serialize 64-deep at L2: 674us — don't) ----
    int* ecnt = (int*)smem;
    int* ncnt = ecnt + EBK;
    int* ebase = ncnt + NBK;
    int* nbase = ebase + EBK;
    int rep = bid & (NREPL - 1);
    for (int i = t; i < EBK; i += 256) ecnt[i] = 0;
    for (int i = t; i < NBK; i += 256) ncnt[i] = 0;
    __syncthreads();
    int start = bid * CHUNK;
    int end = min(start + CHUNK, EE);
    for (int e = start + t; e < end; e += 256) {
      int m = edge_idx[e], n = node_idx[e];
      atomicAdd(&ecnt[m >> 7], 1);
      atomicAdd(&ncnt[n >> 7], 1);
    }
    __syncthreads();
    for (int i = t; i < EBK; i += 256) {
      int c = ecnt[i];
      ebase[i] = c ? atomicAdd(&ecur[rep * EBK + i], c) : 0;
      ecnt[i] = 0;
    }
    for (int i = t; i < NBK; i += 256) {
      int c = ncnt[i];
      nbase[i] = c ? atomicAdd(&ncur[rep * NBK + i], c) : 0;
      ncnt[i] = 0;
    }
    __syncthreads();
    for (int e = start + t; e < end; e += 256) {
      int m = edge_idx[e], n = node_idx[e];
      int eb = m >> 7, nb = n >> 7;
      int p = ebase[eb] + atomicAdd(&ecnt[eb], 1);
      if (p < ECAPR)
        ebins[(size_t)eb * (NREPL * ECAPR) + rep * ECAPR + p] = ((u32)n << 7) | (u32)(m & 127);
      int q = nbase[nb] + atomicAdd(&ncnt[nb], 1);
      if (q < NCAPR)
        nbins[(size_t)nb * (NREPL * NCAPR) + rep * NCAPR + q] = ((u32)m << 7) | (u32)(n & 127);
    }
    return;
  }

  if (bid >= BINA_BLOCKS + GEMM_BLOCKS) {
    // ---- a_edge branch: wave per hyperedge row (4*AEDGE_BLOCKS == MM) ----
    int m = ((bid - BINA_BLOCKS - GEMM_BLOCKS) * 256 + t) >> 6;
    int lane = t & 63;
    float2 wv = ((const float2*)watt2)[lane];
    float2 v = ((const float2*)(he + (size_t)m * FF))[lane];
    float p = v.x * wv.x + v.y * wv.y;
#pragma unroll
    for (int off = 32; off; off >>= 1) p += __shfl_xor(p, off, 64);
    if (lane == 0) a_edge[m] = p;
    return;
  }

  // ---- gemm branch ----
  u16* xl = (u16*)smem;                  // 8 KB swizzled [r][k]
  float* pn = (float*)(smem + 8192);     // 128 B
  if (t < BM) pn[t] = 0.f;
  int row0 = (bid - BINA_BLOCKS) * BM;   // 32*3125 == NN: no bounds checks
  for (int chunk = t; chunk < BM * 32; chunk += 256) {
    int r = chunk >> 5;
    int j = chunk & 31;
    float4 v = ((const float4*)(x + (size_t)(row0 + r) * FF))[j];
    uint2 p;
    p.x = (u32)f2bf(v.x) | ((u32)f2bf(v.y) << 16);
    p.y = (u32)f2bf(v.z) | ((u32)f2bf(v.w) << 16);
    int byte = r * 256 + ((j * 8) ^ ((r & 7) << 4));
    *(uint2*)((char*)xl + byte) = p;
  }
  __syncthreads();

  int wid = t >> 6, lane = t & 63;
  int rt = wid & 1, ch = wid >> 1;
  int r_lo = lane & 15, khalf = lane >> 4;
  f32x4 acc[4];
#pragma unroll
  for (int ct = 0; ct < 4; ++ct) acc[ct] = (f32x4){0.f, 0.f, 0.f, 0.f};

#pragma unroll
  for (int kc = 0; kc < 4; ++kc) {
    int kbyte = kc * 64 + khalf * 16;
    int arow = rt * 16 + r_lo;
    short8v a = *(const short8v*)((const char*)xl + arow * 256 + (kbyte ^ ((arow & 7) << 4)));
#pragma unroll
    for (int ct = 0; ct < 4; ++ct) {
      int brow = ch * 64 + ct * 16 + r_lo;
      short8v b = *(const short8v*)((const char*)WtSwz + brow * 256 + (kbyte ^ ((brow & 7) << 4)));
      acc[ct] = __builtin_amdgcn_mfma_f32_16x16x32_bf16(a, b, acc[ct], 0, 0, 0);
    }
  }

  float att_c[4];
#pragma unroll
  for (int ct = 0; ct < 4; ++ct) att_c[ct] = att[ch * 64 + ct * 16 + r_lo];
  float p[4] = {0.f, 0.f, 0.f, 0.f};
#pragma unroll
  for (int ct = 0; ct < 4; ++ct) {
#pragma unroll
    for (int reg = 0; reg < 4; ++reg) {
      int lrow = rt * 16 + khalf * 4 + reg;
      xw[(size_t)(row0 + lrow) * FF + ch * 64 + ct * 16 + r_lo] = f2bf(acc[ct][reg]);
      p[reg] += acc[ct][reg] * att_c[ct];
    }
  }
#pragma unroll
  for (int off = 1; off <= 8; off <<= 1) {
#pragma unroll
    for (int reg = 0; reg < 4; ++reg) p[reg] += __shfl_xor(p[reg], off, 64);
  }
  if (r_lo == 0) {
#pragma unroll
    for (int reg = 0; reg < 4; ++reg)
      atomicAdd(&pn[rt * 16 + khalf * 4 + reg], p[reg]);
  }
  __syncthreads();
  if (t < BM) a_node[row0 + t] = pn[t];
}

// ---------------------------------------------------------------------------
// k_binB: one block per bucket (edge then node). Inline prefix for the base
// (summing all NREPL replica counters), counting-sort over the 8 replica
// sub-regions into CSR. Emits packed (other_idx, uw) uint2 pairs where
// uw = exp(leaky(a_node[n] + a_edge[m])) (one operand LDS-local per side).
// ---------------------------------------------------------------------------
__global__ __launch_bounds__(256) void k_binB(const u32* __restrict__ ebins,
                                              const int* __restrict__ ecur,
                                              int* __restrict__ edge_ptr,
                                              uint2* __restrict__ pairE,
                                              const u32* __restrict__ nbins,
                                              const int* __restrict__ ncur,
                                              int* __restrict__ node_ptr,
                                              uint2* __restrict__ pairN,
                                              const float* __restrict__ a_node,
                                              const float* __restrict__ a_edge) {
  __shared__ int cnt[128], cur[128], sc[128];
  __shared__ int ps[256];
  __shared__ float loc[128];
  __shared__ int rcnt[NREPL];
  int t = threadIdx.x;
  bool is_edge = blockIdx.x < EBK;
  int b = is_edge ? blockIdx.x : blockIdx.x - EBK;
  const int* curArr = is_edge ? ecur : ncur;     // [NREPL][BK]
  int BK = is_edge ? EBK : NBK;
  int CAPR = is_edge ? ECAPR : NCAPR;
  const u32* binsBase = is_edge ? ebins : nbins; // bucket stride NREPL*CAPR
  int* ptr = is_edge ? edge_ptr : node_ptr;
  uint2* pairArr = is_edge ? pairE : pairN;
  const float* gatherA = is_edge ? a_node : a_edge;  // indexed by 'other'
  int glen = is_edge ? MM : NN;
  int nbk = is_edge ? EBK : NBK;

  if (t < NREPL) rcnt[t] = min(curArr[t * BK + b], CAPR);
  if (t < 128) {
    int g = b * 128 + t;
    loc[t] = (g < glen) ? (is_edge ? a_edge[g] : a_node[g]) : 0.f;
  }

  // inline exclusive prefix: gbase = sum over buckets < b of total counts
  int acc = 0;
  for (int i = t; i < b; i += 256) {
    int s = 0;
#pragma unroll
    for (int r = 0; r < NREPL; ++r) s += min(curArr[r * BK + i], CAPR);
    acc += s;
  }
  ps[t] = acc;
  __syncthreads();
  for (int off = 128; off; off >>= 1) {
    if (t < off) ps[t] += ps[t + off];
    __syncthreads();
  }
  int gbase = ps[0];
  int count = 0;
#pragma unroll
  for (int r = 0; r < NREPL; ++r) count += rcnt[r];

  if (t < 128) cnt[t] = 0;
  __syncthreads();
  for (int r = 0; r < NREPL; ++r) {
    const u32* src = binsBase + (size_t)b * (NREPL * CAPR) + r * CAPR;
    int c = rcnt[r];
    for (int i = t; i < c; i += 256) atomicAdd(&cnt[src[i] & 127], 1);
  }
  __syncthreads();
  if (t < 128) sc[t] = cnt[t];
  __syncthreads();
  for (int off = 1; off < 128; off <<= 1) {
    int u = (t >= off && t < 128) ? sc[t - off] : 0;
    __syncthreads();
    if (t < 128) sc[t] += u;
    __syncthreads();
  }
  if (t < 128) {
    int excl = sc[t] - cnt[t];
    cur[t] = excl;
    int g = b * 128 + t;
    if (g < glen) ptr[g] = gbase + excl;
  }
  if (b == nbk - 1 && t == 0) ptr[glen] = gbase + count;
  __syncthreads();
  for (int r = 0; r < NREPL; ++r) {
    const u32* src = binsBase + (size_t)b * (NREPL * CAPR) + r * CAPR;
    int c = rcnt[r];
    for (int i = t; i < c; i += 256) {
      u32 v = src[i];
      int lo = v & 127;
      int other = (int)(v >> 7);
      int pos = atomicAdd(&cur[lo], 1);
      float uw = __expf(leaky(gatherA[other] + loc[lo]));
      pairArr[gbase + pos] = make_uint2((u32)other, __float_as_uint(uw));
    }
  }
}

// ---------------------------------------------------------------------------
// k_edge_agg: per-edge normalization + node->edge aggregation (wave per edge,
// 4 edges/block exactly). Coalesced ptr prefetch via lane<5 + readlane.
// Writes ef'[m] = ef[m]*invs so node_agg needs no invsE. No max-subtraction.
// ---------------------------------------------------------------------------
__global__ __launch_bounds__(256) void k_edge_agg(const int* __restrict__ edge_ptr,
                                                  const uint2* __restrict__ pairE,
                                                  const u16* __restrict__ xw,
                                                  u16* __restrict__ edge_feat) {
  int wid = threadIdx.x >> 6, lane = threadIdx.x & 63;
  int m = blockIdx.x * 4 + wid;   // 4*gridDim == MM exactly
  int pv_l = (lane < 5) ? edge_ptr[blockIdx.x * 4 + lane] : 0;
  int s0 = __builtin_amdgcn_readlane(pv_l, wid);
  int s1 = __builtin_amdgcn_readlane(pv_l, wid + 1);
  int len = s1 - s0;
  if (len == 0) return;

  float ssum_l = 0.f;
  float accx = 0.f, accy = 0.f;
  for (int base = s0; base < s1; base += 64) {
    int i = base + lane;
    bool valid = i < s1;
    uint2 pv = valid ? pairE[i] : make_uint2(0u, 0u);
    int n_l = (int)pv.x;
    float w_l = __uint_as_float(pv.y);   // 0.0f for invalid lanes
    ssum_l += w_l;
    int cnt = min(64, s1 - base);
    for (int b = 0; b < cnt; b += 16) {
      u32 u[16];
      float wv[16];
#pragma unroll
      for (int j = 0; j < 16; ++j) {
        int n = __builtin_amdgcn_readlane(n_l, b + j);
        wv[j] = readlane_f(w_l, b + j);
        u[j] = *(const u32*)(xw + (size_t)n * FF + 2 * lane);
      }
#pragma unroll
      for (int j = 0; j < 16; ++j) {
        accx += wv[j] * bf2f((u16)u[j]);
        accy += wv[j] * bf2f((u16)(u[j] >> 16));
      }
    }
  }
#pragma unroll
  for (int off = 1; off < 64; off <<= 1) ssum_l += __shfl_xor(ssum_l, off, 64);
  float invs = 1.0f / (ssum_l + 1e-16f);
  float r = invs * invs / (float)len;   // ef' = ef * invs
  u32 packed = (u32)f2bf(accx * r) | ((u32)f2bf(accy * r) << 16);
  *(u32*)(edge_feat + (size_t)m * FF + 2 * lane) = packed;
}

// ---------------------------------------------------------------------------
// k_node_agg: edge->node aggregation, 4 nodes per wave (grid*16 == NN exactly),
// coalesced ptr prefetch, fused BN partial stats. w = uw (ef pre-divided by S).
// ---------------------------------------------------------------------------
__global__ __launch_bounds__(256) void k_node_agg(const int* __restrict__ node_ptr,
                                                  const uint2* __restrict__ pairN,
                                                  const u16* __restrict__ edge_feat,
                                                  const float* __restrict__ bias,
                                                  float* __restrict__ out_f32,
                                                  u16* __restrict__ raw_bf,
                                                  float* __restrict__ bn_partial) {
  __shared__ float4 sd[4][64];
  int wid = threadIdx.x >> 6, lane = threadIdx.x & 63;
  float2 bv = ((const float2*)bias)[lane];
  int n0 = blockIdx.x * 16 + wid * 4;
  int pv_l = (lane < 5) ? node_ptr[n0 + lane] : 0;   // ptr[n0..n0+4]
  float s1x = 0.f, s1y = 0.f, s2x = 0.f, s2y = 0.f;
#pragma unroll
  for (int k = 0; k < 4; ++k) {
    int n = n0 + k;   // grid sized so n < NN always
    int s0 = __builtin_amdgcn_readlane(pv_l, k);
    int s1 = __builtin_amdgcn_readlane(pv_l, k + 1);
    float accx = 0.f, accy = 0.f;
    for (int base = s0; base < s1; base += 64) {
      int i = base + lane;
      bool valid = i < s1;
      uint2 pv = valid ? pairN[i] : make_uint2(0u, 0u);
      int m_l = (int)pv.x;
      float w_l = __uint_as_float(pv.y);   // 0.0f for invalid lanes
      int cnt = min(64, s1 - base);
      for (int b = 0; b < cnt; b += 16) {
        u32 u[16];
        float wv[16];
#pragma unroll
        for (int j = 0; j < 16; ++j) {
          int mm = __builtin_amdgcn_readlane(m_l, b + j);
          wv[j] = readlane_f(w_l, b + j);
          u[j] = *(const u32*)(edge_feat + (size_t)mm * FF + 2 * lane);
        }
#pragma unroll
        for (int j = 0; j < 16; ++j) {
          accx += wv[j] * bf2f((u16)u[j]);
          accy += wv[j] * bf2f((u16)(u[j] >> 16));
        }
      }
    }
    int deg = s1 - s0;
    float dinv = deg > 0 ? 1.0f / (float)deg : 0.f;
    float ox = accx * dinv + bv.x;
    float oy = accy * dinv + bv.y;
    if (raw_bf) {
      *(u32*)(raw_bf + (size_t)n * FF + 2 * lane) = (u32)f2bf(ox) | ((u32)f2bf(oy) << 16);
    } else {
      ((float2*)(out_f32 + (size_t)n * FF))[lane] = make_float2(ox, oy);
    }
    s1x += ox; s1y += oy;
    s2x += ox * ox; s2y += oy * oy;
  }
  sd[wid][lane] = make_float4(s1x, s1y, s2x, s2y);
  __syncthreads();
  if (wid == 0) {
    float4 a0 = sd[0][lane], a1 = sd[1][lane], a2 = sd[2][lane], a3 = sd[3][lane];
    float4 s;
    s.x = a0.x + a1.x + a2.x + a3.x;
    s.y = a0.y + a1.y + a2.y + a3.y;
    s.z = a0.z + a1.z + a2.z + a3.z;
    s.w = a0.w + a1.w + a2.w + a3.w;
    float* bp = bn_partial + (blockIdx.x & (NREP - 1)) * 256;
    atomicAdd(bp + 2 * lane, s.x);
    atomicAdd(bp + 2 * lane + 1, s.y);
    atomicAdd(bp + 128 + 2 * lane, s.z);
    atomicAdd(bp + 128 + 2 * lane + 1, s.w);
  }
}

// ---------------------------------------------------------------------------
// k_bn_final: reduce bn_partial replicas -> BN scale/shift
// ---------------------------------------------------------------------------
__global__ void k_bn_final(const float* __restrict__ bn_partial, const float* __restrict__ gamma,
                           const float* __restrict__ beta, float* __restrict__ ss) {
  int c = threadIdx.x; // 128
  float s1 = 0.f, s2 = 0.f;
  for (int r = 0; r < NREP; ++r) {
    s1 += bn_partial[r * 256 + c];
    s2 += bn_partial[r * 256 + 128 + c];
  }
  float mu = s1 * (1.0f / NN);
  float var = s2 * (1.0f / NN) - mu * mu;
  var = fmaxf(var, 0.f);
  float sc = gamma[c] * rsqrtf(var + 1e-5f);
  ss[c] = sc;
  ss[FF + c] = beta[c] - mu * sc;
}

// ---------------------------------------------------------------------------
// k_finalize: BN + ELU + residual. Reads raw (bf16 if raw_bf, else out in place).
// ---------------------------------------------------------------------------
__global__ __launch_bounds__(256) void k_finalize(float* __restrict__ out,
                                                  const u16* __restrict__ raw_bf,
                                                  const float* __restrict__ x,
                                                  const float* __restrict__ ss) {
  int idx = blockIdx.x * 256 + threadIdx.x;  // float4 index
  float4 v;
  if (raw_bf) {
    ushort4 rv = *(const ushort4*)(raw_bf + (size_t)idx * 4);
    v = make_float4(bf2f(rv.x), bf2f(rv.y), bf2f(rv.z), bf2f(rv.w));
  } else {
    v = ((const float4*)out)[idx];
  }
  float4 xr = ((const float4*)x)[idx];
  int cb = (idx * 4) & 127;
  float4 sc = *(const float4*)(ss + cb);
  float4 sh = *(const float4*)(ss + FF + cb);
  v.x = fmaf(v.x, sc.x, sh.x);
  v.y = fmaf(v.y, sc.y, sh.y);
  v.z = fmaf(v.z, sc.z, sh.z);
  v.w = fmaf(v.w, sc.w, sh.w);
  v.x = v.x > 0.f ? v.x : expm1f(v.x);
  v.y = v.y > 0.f ? v.y : expm1f(v.y);
  v.z = v.z > 0.f ? v.z : expm1f(v.z);
  v.w = v.w > 0.f ? v.w : expm1f(v.w);
  v.x += xr.x; v.y += xr.y; v.z += xr.z; v.w += xr.w;
  ((float4*)out)[idx] = v;
}

// ---------------------------------------------------------------------------
extern "C" void kernel_launch(void* const* d_in, const int* in_sizes, int n_in,
                              void* d_out, int out_size, void* d_ws, size_t ws_size,
                              hipStream_t stream) {
  const float* x     = (const float*)d_in[0];
  const float* he    = (const float*)d_in[1];
  const float* W     = (const float*)d_in[2];
  const float* att   = (const float*)d_in[3];
  const float* bias  = (const float*)d_in[4];
  const float* gamma = (const float*)d_in[5];
  const float* beta  = (const float*)d_in[6];
  const int* node_idx = (const int*)d_in[7];
  const int* edge_idx = (const int*)d_in[8];
  float* out = (float*)d_out;

  char* w = (char*)d_ws;
  auto alloc = [&](size_t bytes) -> char* {
    char* p = w;
    w += (bytes + 255) & ~(size_t)255;
    return p;
  };
  u16*   xw        = (u16*)  alloc((size_t)NN * FF * 2);
  float* a_node    = (float*)alloc((size_t)NN * 4);
  float* a_edge    = (float*)alloc((size_t)MM * 4);
  u16*   WtSwz     = (u16*)  alloc((size_t)FF * FF * 2);
  float* watt2     = (float*)alloc(FF * 4);
  u16*   edge_feat = (u16*)  alloc((size_t)MM * FF * 2);
  int* edge_ptr    = (int*)  alloc((size_t)(MM + 1) * 4);
  int* node_ptr    = (int*)  alloc((size_t)(NN + 1) * 4);
  uint2* pairE     = (uint2*)alloc((size_t)EE * 8);
  uint2* pairN     = (uint2*)alloc((size_t)EE * 8);
  int* ecur        = (int*)  alloc((size_t)NREPL * EBK * 4);
  int* ncur        = (int*)  alloc((size_t)NREPL * NBK * 4);
  u32* ebins       = (u32*)  alloc((size_t)EBK * NREPL * ECAPR * 4);
  u32* nbins       = (u32*)  alloc((size_t)NBK * NREPL * NCAPR * 4);
  float* bn_partial= (float*)alloc((size_t)NREP * 256 * 4);
  float* ss        = (float*)alloc(2 * FF * 4);
  u16*   raw_cand  = (u16*)  alloc((size_t)NN * FF * 2);  // bf16 raw staging (optional)
  size_t need = (size_t)(w - (char*)d_ws);
  u16* raw_bf = (need <= ws_size) ? raw_cand : (u16*)nullptr;

  k_prep<<<64, 256, 0, stream>>>(W, att, watt2, WtSwz, ecur, ncur, bn_partial);
  k_mega<<<BINA_BLOCKS + GEMM_BLOCKS + AEDGE_BLOCKS, 256, 0, stream>>>(
      x, WtSwz, att, xw, a_node, he, watt2, a_edge,
      node_idx, edge_idx, ecur, ncur, ebins, nbins);

  k_binB<<<EBK + NBK, 256, 0, stream>>>(ebins, ecur, edge_ptr, pairE,
                                        nbins, ncur, node_ptr, pairN,
                                        a_node, a_edge);

  k_edge_agg<<<MM / 4, 256, 0, stream>>>(edge_ptr, pairE, xw, edge_feat);
  k_node_agg<<<NN / 16, 256, 0, stream>>>(node_ptr, pairN, edge_feat, bias, out, raw_bf, bn_partial);
  k_bn_final<<<1, 128, 0, stream>>>(bn_partial, gamma, beta, ss);
  k_finalize<<<(NN * FF / 4 + 255) / 256, 256, 0, stream>>>(out, raw_bf, x, ss);
}